// Round 3
// baseline (14667.862 us; speedup 1.0000x reference)
//
#include <hip/hip_runtime.h>

typedef __attribute__((ext_vector_type(4))) float f32x4;
typedef __attribute__((ext_vector_type(8))) _Float16 f16x8;
typedef __attribute__((ext_vector_type(4))) _Float16 f16x4;
typedef __attribute__((ext_vector_type(4))) unsigned int u32x4;

__device__ __forceinline__ unsigned short f2bf(float f) {
  unsigned int u = __builtin_bit_cast(unsigned int, f);
  u += 0x7fffu + ((u >> 16) & 1u);
  return (unsigned short)(u >> 16);
}
__device__ __forceinline__ float bf2f(unsigned short u) {
  return __builtin_bit_cast(float, ((unsigned int)u) << 16);
}

// LDS swizzle helpers: return BYTE offset into the tile. Same helper used by
// writer and reader => mapping always consistent (bijective within each row).
__device__ __forceinline__ int kbyte(int row, int off) {   // K tile [128][64] f16 (128B rows)
  return (row << 7) + (off ^ ((row & 7) << 4));
}
__device__ __forceinline__ int vbyte(int d, int off) {     // V^T tile [64][128] f16 (256B rows)
  return (d << 8) + (off ^ ((((d & 7) ^ ((d >> 3) & 7))) << 4));
}
__device__ __forceinline__ int wbyte(int row, int off) {   // w tile [128][128] f16 (256B rows)
  return (row << 8) + (off ^ ((row & 7) << 4));
}
__device__ __forceinline__ int gbyte(int row, int off) {   // gemm tiles [128][32] f16 (64B rows)
  return (row << 6) + (off ^ ((row & 3) << 4));
}

// ---------------------------------------------------------------- converts
__global__ __launch_bounds__(256) void f32_to_f16_k(const float* __restrict__ src,
                                                    _Float16* __restrict__ dst, int n4) {
  int i = threadIdx.x + blockIdx.x * 256;
  if (i < n4) {
    float4 v = ((const float4*)src)[i];
    f16x4 o;
    o[0] = (_Float16)v.x; o[1] = (_Float16)v.y; o[2] = (_Float16)v.z; o[3] = (_Float16)v.w;
    ((f16x4*)dst)[i] = o;
  }
}

__global__ __launch_bounds__(256) void bias_prep(const float* __restrict__ b_ih, const float* __restrict__ b_hh,
                                                 const float* __restrict__ bq, const float* __restrict__ bk,
                                                 const float* __restrict__ bv,
                                                 float* __restrict__ bsum, float* __restrict__ bqkv) {
  int i = threadIdx.x + blockIdx.x * 256;
  if (i < 4096) bsum[i] = b_ih[i] + b_hh[i];
  if (i < 3072) bqkv[i] = (i < 1024) ? bq[i] : (i < 2048 ? bk[i - 1024] : bv[i - 2048]);
}

__global__ __launch_bounds__(256) void init_kernel(unsigned long long* __restrict__ ebuf) {
  int i = threadIdx.x + blockIdx.x * 256;
  if (i < 1024) ebuf[i] = 0ull;   // tag 0, h = 0 (both parity buffers)
}

// ---------------------------------------------------------------- GEMM  C[m][n] = sum_k A[m][k]*B[n][k] (+bias[n])
__global__ __launch_bounds__(256)
void gemm_nt(const _Float16* __restrict__ A, const _Float16* __restrict__ B,
             const float* __restrict__ bias, float* __restrict__ Cf, _Float16* __restrict__ Ch,
             int M, int N, int K) {
  __shared__ _Float16 a_lds[128 * 32];
  __shared__ _Float16 b_lds[128 * 32];
  const int tid = threadIdx.x;
  const int wave = tid >> 6, lane = tid & 63;
  const int l15 = lane & 15, l4 = lane >> 4;
  const int m0 = blockIdx.y * 128, n0 = blockIdx.x * 128;
  const int wm = (wave & 1) * 64, wn = (wave >> 1) * 64;
  f32x4 acc[4][4] = {};
  for (int k0 = 0; k0 < K; k0 += 32) {
    __syncthreads();
#pragma unroll
    for (int i = 0; i < 2; ++i) {
      int L = tid + i * 256;
      int r = L >> 2, cb = (L & 3) * 16;   // byte offset in row
      *(u32x4*)((char*)a_lds + gbyte(r, cb)) = *(const u32x4*)&A[(long)(m0 + r) * K + k0 + (cb >> 1)];
      *(u32x4*)((char*)b_lds + gbyte(r, cb)) = *(const u32x4*)&B[(long)(n0 + r) * K + k0 + (cb >> 1)];
    }
    __syncthreads();
    f16x8 af[4], bfr[4];
#pragma unroll
    for (int mf = 0; mf < 4; ++mf)
      af[mf] = *(const f16x8*)((const char*)a_lds + gbyte(wm + mf * 16 + l15, l4 * 16));
#pragma unroll
    for (int nf = 0; nf < 4; ++nf)
      bfr[nf] = *(const f16x8*)((const char*)b_lds + gbyte(wn + nf * 16 + l15, l4 * 16));
#pragma unroll
    for (int mf = 0; mf < 4; ++mf)
#pragma unroll
      for (int nf = 0; nf < 4; ++nf)
        acc[mf][nf] = __builtin_amdgcn_mfma_f32_16x16x32_f16(af[mf], bfr[nf], acc[mf][nf], 0, 0, 0);
  }
#pragma unroll
  for (int mf = 0; mf < 4; ++mf)
#pragma unroll
    for (int nf = 0; nf < 4; ++nf)
#pragma unroll
      for (int j = 0; j < 4; ++j) {
        int row = m0 + wm + mf * 16 + l4 * 4 + j;
        int col = n0 + wn + nf * 16 + l15;
        float v = acc[mf][nf][j];
        if (bias) v += bias[col];
        if (Cf) Cf[(long)row * N + col] = v;
        else Ch[(long)row * N + col] = (_Float16)v;
      }
}

// ---------------------------------------------------------------- LSTM persistent kernel
// 256 WGs (1/CU). WG wg owns h-units j0=wg*4..+3 (16 W_hh rows in LDS, f16).
// Device-wide step exchange: 512 x 8B entries, double-buffered by step parity.
// entry = (step_tag << 32) | bf16(h_even) | bf16(h_odd)<<16, ONE relaxed
// agent-scope 8B atomic store => tag visibility implies data validity.
__global__ __launch_bounds__(256)
void lstm_kernel(const float* __restrict__ Whh, const float* __restrict__ xproj,
                 _Float16* __restrict__ hs, unsigned long long* __restrict__ ebuf) {
  __shared__ _Float16 Wl[16 * 1032];   // padded stride breaks bank alias
  __shared__ float h_lds[1024];
  __shared__ float gates_lds[16];
  __shared__ float c_lds[4];
  const int tid = threadIdx.x;
  const int wg = blockIdx.x;
  const int j0 = wg * 4;
  for (int i = tid; i < 16 * 1024; i += 256) {
    int r = i >> 10, k = i & 1023;
    int grow = (r >> 2) * 1024 + j0 + (r & 3);  // gate g = r>>2, unit jj = r&3
    Wl[r * 1032 + k] = (_Float16)Whh[(long)grow * 1024 + k];
  }
  if (tid < 4) c_lds[tid] = 0.f;
  __syncthreads();
  const int row = tid >> 4, kc = tid & 15;
  for (int t = 0; t < 4096; ++t) {
    float gx0 = 0.f, gx1 = 0.f, gx2 = 0.f, gx3 = 0.f;
    if (tid < 4) {                      // prefetch x-proj; overlaps the poll
      const float* xp = xproj + (long)t * 4096 + j0 + tid;
      gx0 = xp[0]; gx1 = xp[1024]; gx2 = xp[2048]; gx3 = xp[3072];
    }
    unsigned long long* bcur = ebuf + (long)(t & 1) * 512;
    unsigned long long e0, e1;
    const unsigned tg = (unsigned)t;
    while (true) {
      e0 = __hip_atomic_load(&bcur[2 * tid], __ATOMIC_RELAXED, __HIP_MEMORY_SCOPE_AGENT);
      e1 = __hip_atomic_load(&bcur[2 * tid + 1], __ATOMIC_RELAXED, __HIP_MEMORY_SCOPE_AGENT);
      if ((unsigned)(e0 >> 32) == tg && (unsigned)(e1 >> 32) == tg) break;
    }
    f32x4 hv;
    hv[0] = bf2f((unsigned short)e0);
    hv[1] = bf2f((unsigned short)(e0 >> 16));
    hv[2] = bf2f((unsigned short)e1);
    hv[3] = bf2f((unsigned short)(e1 >> 16));
    *(f32x4*)&h_lds[tid * 4] = hv;
    __syncthreads();
    float acc = 0.f;
    const _Float16* wrow = &Wl[row * 1032];
#pragma unroll
    for (int i = 0; i < 16; ++i) {
      int k = kc * 4 + i * 64;
      f16x4 wv = *(const f16x4*)&wrow[k];
      f32x4 hh = *(const f32x4*)&h_lds[k];
      acc += (float)wv[0] * hh[0] + (float)wv[1] * hh[1] + (float)wv[2] * hh[2] + (float)wv[3] * hh[3];
    }
    acc += __shfl_xor(acc, 1); acc += __shfl_xor(acc, 2);
    acc += __shfl_xor(acc, 4); acc += __shfl_xor(acc, 8);
    if (kc == 0) gates_lds[row] = acc;
    __syncthreads();
    if (tid < 4) {
      float gi = gates_lds[tid] + gx0;
      float gf = gates_lds[4 + tid] + gx1;
      float gg = gates_lds[8 + tid] + gx2;
      float go = gates_lds[12 + tid] + gx3;
      float ii = 1.f / (1.f + __expf(-gi));
      float ff = 1.f / (1.f + __expf(-gf));
      float gv = 1.f - 2.f / (__expf(2.f * gg) + 1.f);
      float oo = 1.f / (1.f + __expf(-go));
      float c = ff * c_lds[tid] + ii * gv;
      c_lds[tid] = c;
      float hn = oo * (1.f - 2.f / (__expf(2.f * c) + 1.f));
      hs[(long)t * 1024 + j0 + tid] = (_Float16)hn;
      unsigned hb = f2bf(hn);
      unsigned hp = (unsigned)__shfl_xor((int)hb, 1);
      if ((tid & 1) == 0) {
        unsigned long long ev = ((unsigned long long)(tg + 1) << 32) |
                                (unsigned long long)(hb | (hp << 16));
        __hip_atomic_store(&ebuf[(long)((t + 1) & 1) * 512 + wg * 2 + (tid >> 1)], ev,
                           __ATOMIC_RELAXED, __HIP_MEMORY_SCOPE_AGENT);
      }
    }
  }
}

// ---------------------------------------------------------------- RoPE + head-major split
__global__ __launch_bounds__(256)
void rope_kernel(const _Float16* __restrict__ qkv, const float* __restrict__ cosb,
                 const float* __restrict__ sinb, _Float16* __restrict__ qh,
                 _Float16* __restrict__ kh, _Float16* __restrict__ vh) {
  int t = blockIdx.x;
  for (int i = threadIdx.x; i < 1024; i += 256) {
    int h = i >> 6, d = i & 63;
    float c = cosb[t * 64 + d], s = sinb[t * 64 + d];
    int pd = (d < 32) ? d + 32 : d - 32;
    float sgn = (d < 32) ? -1.f : 1.f;
    float qv = (float)qkv[(long)t * 3072 + i];
    float qp = (float)qkv[(long)t * 3072 + h * 64 + pd];
    float kv = (float)qkv[(long)t * 3072 + 1024 + i];
    float kp = (float)qkv[(long)t * 3072 + 1024 + h * 64 + pd];
    long o = ((long)h * 4096 + t) * 64 + d;
    qh[o] = (_Float16)(qv * c + sgn * qp * s);
    kh[o] = (_Float16)(kv * c + sgn * kp * s);
    vh[o] = qkv[(long)t * 3072 + 2048 + i];
  }
}

// ---------------------------------------------------------------- attention sweep 1: row max + denom
__global__ __launch_bounds__(256)
void attn_stats(const _Float16* __restrict__ Qh, const _Float16* __restrict__ Kh,
                float* __restrict__ statm, float* __restrict__ statl) {
  __shared__ _Float16 k_lds[128 * 64];
  __shared__ float redm[128 * 2];
  __shared__ float redl[128 * 2];
  const int tid = threadIdx.x, wave = tid >> 6, lane = tid & 63;
  const int l15 = lane & 15, l4 = lane >> 4;
  const int h = blockIdx.y, q0 = blockIdx.x * 128;
  const int wm = (wave & 1) * 64, wn = (wave >> 1) * 64;
  const _Float16* Q = Qh + ((long)h * 4096 + q0) * 64;
  const _Float16* Kp = Kh + (long)h * 4096 * 64;
  f16x8 qf[4][2];
#pragma unroll
  for (int mf = 0; mf < 4; ++mf)
#pragma unroll
    for (int kcq = 0; kcq < 2; ++kcq)
      qf[mf][kcq] = *(const f16x8*)&Q[(long)(wm + mf * 16 + l15) * 64 + kcq * 32 + l4 * 8];
  float m_run[16], l_run[16];
#pragma unroll
  for (int i = 0; i < 16; ++i) { m_run[i] = -1e30f; l_run[i] = 0.f; }
  for (int kv0 = 0; kv0 <= q0; kv0 += 128) {
    __syncthreads();
#pragma unroll
    for (int i = 0; i < 4; ++i) {                 // full 128x64 tile
      int L = tid + i * 256;
      int r = L >> 3, cb = (L & 7) * 16;
      *(u32x4*)((char*)k_lds + kbyte(r, cb)) = *(const u32x4*)&Kp[(long)(kv0 + r) * 64 + (cb >> 1)];
    }
    __syncthreads();
    f32x4 s[4][4] = {};
#pragma unroll
    for (int nf = 0; nf < 4; ++nf)
#pragma unroll
      for (int kcq = 0; kcq < 2; ++kcq) {
        f16x8 kf = *(const f16x8*)((const char*)k_lds + kbyte(wn + nf * 16 + l15, kcq * 64 + l4 * 16));
#pragma unroll
        for (int mf = 0; mf < 4; ++mf)
          s[mf][nf] = __builtin_amdgcn_mfma_f32_16x16x32_f16(qf[mf][kcq], kf, s[mf][nf], 0, 0, 0);
      }
    bool diag = (kv0 == q0);
#pragma unroll
    for (int mf = 0; mf < 4; ++mf)
#pragma unroll
      for (int j = 0; j < 4; ++j) {
        int idx = mf * 4 + j;
        int row_l = wm + mf * 16 + l4 * 4 + j;
        float v[4];
        float mx = -1e30f;
#pragma unroll
        for (int nf = 0; nf < 4; ++nf) {
          float val = s[mf][nf][j] * 0.125f;
          int col_l = wn + nf * 16 + l15;
          if (diag && col_l > row_l) val = -3e30f;
          v[nf] = val;
          mx = fmaxf(mx, val);
        }
        for (int d = 1; d < 16; d <<= 1) mx = fmaxf(mx, __shfl_xor(mx, d));
        float mnew = fmaxf(m_run[idx], mx);
        float sum = 0.f;
#pragma unroll
        for (int nf = 0; nf < 4; ++nf) {
          float e = __expf(v[nf] - mnew);
          if (v[nf] < -1e29f) e = 0.f;
          sum += e;
        }
        for (int d = 1; d < 16; d <<= 1) sum += __shfl_xor(sum, d);
        l_run[idx] = l_run[idx] * __expf(m_run[idx] - mnew) + sum;
        m_run[idx] = mnew;
      }
  }
  if (l15 == 0) {
#pragma unroll
    for (int mf = 0; mf < 4; ++mf)
#pragma unroll
      for (int j = 0; j < 4; ++j) {
        int row_l = wm + mf * 16 + l4 * 4 + j;
        redm[row_l * 2 + (wave >> 1)] = m_run[mf * 4 + j];
        redl[row_l * 2 + (wave >> 1)] = l_run[mf * 4 + j];
      }
  }
  __syncthreads();
  if (tid < 128) {
    float m0v = redm[tid * 2], m1v = redm[tid * 2 + 1];
    float M = fmaxf(m0v, m1v);
    float L = redl[tid * 2] * __expf(m0v - M) + redl[tid * 2 + 1] * __expf(m1v - M);
    statm[(long)h * 4096 + q0 + tid] = M;
    statl[(long)h * 4096 + q0 + tid] = 1.f / L;
  }
}

// ---------------------------------------------------------------- attention sweep 2: write w + O = w@V
__global__ __launch_bounds__(256)
void attn_wpv(const _Float16* __restrict__ Qh, const _Float16* __restrict__ Kh,
              const _Float16* __restrict__ Vh, const float* __restrict__ statm,
              const float* __restrict__ statl, float* __restrict__ Wout,
              _Float16* __restrict__ Obf) {
  __shared__ _Float16 kv_lds[128 * 64];   // K tile [128][64]; then V^T [64][128]
  __shared__ _Float16 w_lds[128 * 128];
  const int tid = threadIdx.x, wave = tid >> 6, lane = tid & 63;
  const int l15 = lane & 15, l4 = lane >> 4;
  const int h = blockIdx.y, q0 = blockIdx.x * 128;
  const int wm = (wave & 1) * 64, wn = (wave >> 1) * 64;     // S-tile split
  const int wm2 = (wave & 1) * 64, wn2 = (wave >> 1) * 32;   // O-tile split
  const _Float16* Q = Qh + ((long)h * 4096 + q0) * 64;
  const _Float16* Kp = Kh + (long)h * 4096 * 64;
  const _Float16* Vp = Vh + (long)h * 4096 * 64;
  float* WoutH = Wout + ((long)h * 4096 + q0) * 4096;
  f16x8 qf[4][2];
#pragma unroll
  for (int mf = 0; mf < 4; ++mf)
#pragma unroll
    for (int kcq = 0; kcq < 2; ++kcq)
      qf[mf][kcq] = *(const f16x8*)&Q[(long)(wm + mf * 16 + l15) * 64 + kcq * 32 + l4 * 8];
  float M[16], IL[16];
#pragma unroll
  for (int mf = 0; mf < 4; ++mf)
#pragma unroll
    for (int j = 0; j < 4; ++j) {
      int row_l = wm + mf * 16 + l4 * 4 + j;
      M[mf * 4 + j] = statm[(long)h * 4096 + q0 + row_l];
      IL[mf * 4 + j] = statl[(long)h * 4096 + q0 + row_l];
    }
  f32x4 acco[4][2] = {};
  for (int kv0 = 0; kv0 <= q0; kv0 += 128) {
    __syncthreads();
#pragma unroll
    for (int i = 0; i < 4; ++i) {                 // full 128x64 K tile
      int L = tid + i * 256;
      int r = L >> 3, cb = (L & 7) * 16;
      *(u32x4*)((char*)kv_lds + kbyte(r, cb)) = *(const u32x4*)&Kp[(long)(kv0 + r) * 64 + (cb >> 1)];
    }
    __syncthreads();
    f32x4 s[4][4] = {};
#pragma unroll
    for (int nf = 0; nf < 4; ++nf)
#pragma unroll
      for (int kcq = 0; kcq < 2; ++kcq) {
        f16x8 kf = *(const f16x8*)((const char*)kv_lds + kbyte(wn + nf * 16 + l15, kcq * 64 + l4 * 16));
#pragma unroll
        for (int mf = 0; mf < 4; ++mf)
          s[mf][nf] = __builtin_amdgcn_mfma_f32_16x16x32_f16(qf[mf][kcq], kf, s[mf][nf], 0, 0, 0);
      }
    bool diag = (kv0 == q0);
#pragma unroll
    for (int mf = 0; mf < 4; ++mf)
#pragma unroll
      for (int nf = 0; nf < 4; ++nf)
#pragma unroll
        for (int j = 0; j < 4; ++j) {
          int row_l = wm + mf * 16 + l4 * 4 + j;
          int col_l = wn + nf * 16 + l15;
          float val = s[mf][nf][j] * 0.125f;
          float wv = 0.f;
          if (!(diag && col_l > row_l)) wv = __expf(val - M[mf * 4 + j]) * IL[mf * 4 + j];
          WoutH[(long)row_l * 4096 + kv0 + col_l] = wv;
          *(_Float16*)((char*)w_lds + wbyte(row_l, col_l * 2)) = (_Float16)wv;
        }
    __syncthreads();
#pragma unroll
    for (int i = 0; i < 4; ++i) {                 // stage V^T [64][128]
      int L = tid + i * 256;
      int r = L >> 3, ch = (L & 7) * 8;           // r = k row, ch = d base
      u32x4 vv = *(const u32x4*)&Vp[(long)(kv0 + r) * 64 + ch];
      const _Float16* ve = (const _Float16*)&vv;
#pragma unroll
      for (int e = 0; e < 8; ++e)
        *(_Float16*)((char*)kv_lds + vbyte(ch + e, 2 * r)) = ve[e];
    }
    __syncthreads();
#pragma unroll
    for (int kc2 = 0; kc2 < 4; ++kc2) {
      f16x8 vf[2];
#pragma unroll
      for (int nf = 0; nf < 2; ++nf)
        vf[nf] = *(const f16x8*)((const char*)kv_lds + vbyte(wn2 + nf * 16 + l15, kc2 * 64 + l4 * 16));
#pragma unroll
      for (int mf = 0; mf < 4; ++mf) {
        f16x8 wf = *(const f16x8*)((const char*)w_lds + wbyte(wm2 + mf * 16 + l15, kc2 * 64 + l4 * 16));
#pragma unroll
        for (int nf = 0; nf < 2; ++nf)
          acco[mf][nf] = __builtin_amdgcn_mfma_f32_16x16x32_f16(wf, vf[nf], acco[mf][nf], 0, 0, 0);
      }
    }
  }
  {  // zero the strictly-above-diagonal remainder, vectorized float4 rows
    const int zstart = q0 + 128;
    const int zn = (4096 - zstart) >> 2;
    f32x4 z4 = {0.f, 0.f, 0.f, 0.f};
    for (int r = 0; r < 128; ++r) {
      f32x4* dst = (f32x4*)&WoutH[(long)r * 4096 + zstart];
      for (int c = tid; c < zn; c += 256) dst[c] = z4;
    }
  }
#pragma unroll
  for (int mf = 0; mf < 4; ++mf)
#pragma unroll
    for (int nf = 0; nf < 2; ++nf)
#pragma unroll
      for (int j = 0; j < 4; ++j) {
        int trow = q0 + wm2 + mf * 16 + l4 * 4 + j;
        int dcol = wn2 + nf * 16 + l15;
        Obf[(long)trow * 1024 + h * 64 + dcol] = (_Float16)acco[mf][nf][j];
      }
}

// ---------------------------------------------------------------- launch
extern "C" void kernel_launch(void* const* d_in, const int* in_sizes, int n_in,
                              void* d_out, int out_size, void* d_ws, size_t ws_size,
                              hipStream_t stream) {
  (void)in_sizes; (void)n_in; (void)out_size; (void)ws_size;
  const float* hid  = (const float*)d_in[0];
  const float* cosb = (const float*)d_in[1];
  const float* sinb = (const float*)d_in[2];
  const float* W_ih = (const float*)d_in[4];
  const float* W_hh = (const float*)d_in[5];
  const float* b_ih = (const float*)d_in[6];
  const float* b_hh = (const float*)d_in[7];
  const float* Wq = (const float*)d_in[8];
  const float* bq = (const float*)d_in[9];
  const float* Wk = (const float*)d_in[10];
  const float* bk = (const float*)d_in[11];
  const float* Wv = (const float*)d_in[12];
  const float* bv = (const float*)d_in[13];
  const float* Wo = (const float*)d_in[14];

  float* outf = (float*)d_out;
  float* wout = outf + 4194304;   // w region of d_out: 16*4096*4096 fp32 = 1 GiB
  // Scratch aliased into the w region (all dead before attn_wpv overwrites it):
  char* wb = (char*)wout;
  float*    xproj  = (float*)(wb);                        // 64 MB
  _Float16* qkv_h  = (_Float16*)(wb + (64u  << 20));      // 24 MB
  _Float16* hid_h  = (_Float16*)(wb + (96u  << 20));      // 8 MB
  _Float16* wih_h  = (_Float16*)(wb + (112u << 20));      // 8 MB
  _Float16* wqkv_h = (_Float16*)(wb + (128u << 20));      // 6 MB
  _Float16* hs_h   = (_Float16*)(wb + (144u << 20));      // 8 MB
  float*    bsum   = (float*)(wb + (160u << 20));         // 16 KB
  float*    bqkv   = (float*)(wb + (161u << 20));         // 12 KB

  char* ws = (char*)d_ws;                                 // ~40 MB used
  _Float16*           wo_h  = (_Float16*)(ws);            // 2 MB
  unsigned long long* ebuf  = (unsigned long long*)(ws + (4u << 20));  // 8 KB
  float*    statm = (float*)(ws + (5u << 20));            // 256 KB
  float*    statl = (float*)(ws + (6u << 20));            // 256 KB
  _Float16* qh    = (_Float16*)(ws + (8u  << 20));        // 8 MB
  _Float16* kh    = (_Float16*)(ws + (16u << 20));        // 8 MB
  _Float16* vh    = (_Float16*)(ws + (24u << 20));        // 8 MB
  _Float16* obf   = (_Float16*)(ws + (32u << 20));        // 8 MB

  init_kernel<<<4, 256, 0, stream>>>(ebuf);
  f32_to_f16_k<<<4096, 256, 0, stream>>>(hid, hid_h, 1048576);
  f32_to_f16_k<<<4096, 256, 0, stream>>>(W_ih, wih_h, 1048576);
  f32_to_f16_k<<<1024, 256, 0, stream>>>(Wq, wqkv_h, 262144);
  f32_to_f16_k<<<1024, 256, 0, stream>>>(Wk, wqkv_h + 1048576, 262144);
  f32_to_f16_k<<<1024, 256, 0, stream>>>(Wv, wqkv_h + 2097152, 262144);
  f32_to_f16_k<<<1024, 256, 0, stream>>>(Wo, wo_h, 262144);
  bias_prep<<<16, 256, 0, stream>>>(b_ih, b_hh, bq, bk, bv, bsum, bqkv);

  // x_proj = hidden @ W_ih^T + (b_ih + b_hh)   [4096 x 4096] fp32
  gemm_nt<<<dim3(32, 32), 256, 0, stream>>>(hid_h, wih_h, bsum, xproj, nullptr, 4096, 4096, 1024);
  // sequential LSTM scan -> hs (f16)
  lstm_kernel<<<256, 256, 0, stream>>>(W_hh, xproj, hs_h, ebuf);
  // qkv = hs @ [Wq;Wk;Wv]^T + b   [4096 x 3072] f16
  gemm_nt<<<dim3(24, 32), 256, 0, stream>>>(hs_h, wqkv_h, bqkv, nullptr, qkv_h, 4096, 3072, 1024);
  rope_kernel<<<4096, 256, 0, stream>>>(qkv_h, cosb, sinb, qh, kh, vh);
  attn_stats<<<dim3(32, 16), 256, 0, stream>>>(qh, kh, statm, statl);
  attn_wpv<<<dim3(32, 16), 256, 0, stream>>>(qh, kh, vh, statm, statl, wout, obf);
  // attn_output = O @ Wo^T   [4096 x 1024] fp32 -> d_out
  gemm_nt<<<dim3(8, 32), 256, 0, stream>>>(obf, wo_h, nullptr, outf, nullptr, 4096, 1024, 1024);
}